// Round 2
// baseline (857.384 us; speedup 1.0000x reference)
//
#include <hip/hip_runtime.h>
#include <math.h>

// N_OBJ=2048, IN_DIM=128, MID_DIM=256, OUT_DIM=1
// Grouped per-object GEMV stack, memory-bound (~773 MB streamed once).
// Round 1 lesson: row-per-thread is uncoalesced (lanes 1 KB apart) -> 0.9 TB/s.
// This version: wave-per-row, lanes stride K -> every load instruction is one
// contiguous 512B/1KB segment. Roofline ~123 us @ 6.3 TB/s.

#define N_OBJ   2048
#define IN_DIM  128
#define MID_DIM 256

__global__ __launch_bounds__(256, 8) void mlp_grouped_kernel(
    const float* __restrict__ x,   // [O, 128]
    const float* __restrict__ W1,  // [O, 256, 128]
    const float* __restrict__ b1,  // [O, 256]
    const float* __restrict__ W2,  // [O, 256, 256]
    const float* __restrict__ b2,  // [O, 256]
    const float* __restrict__ W3,  // [O, 1, 256]
    const float* __restrict__ b3,  // [O, 1]
    float* __restrict__ out)       // [O]
{
    const int o = blockIdx.x;
    const int t = threadIdx.x;
    const int w = t >> 6;   // wave id 0..3
    const int l = t & 63;   // lane id

    __shared__ __align__(16) float s_x[IN_DIM];
    __shared__ __align__(16) float s_y1[MID_DIM];
    __shared__ __align__(16) float s_y2[MID_DIM];
    __shared__ float s_red[4];

    // Stage x[o,:]: 32 float4 loads, coalesced.
    if (t < IN_DIM / 4)
        ((float4*)s_x)[t] = ((const float4*)(x + (size_t)o * IN_DIM))[t];
    __syncthreads();

    // ----- Layer 1: y1[r] = dot(x, W1[o,r,:]) + b1[o,r]  (NO activation) -----
    // Wave w handles rows [w*64, w*64+64). Lane l reads float2 at k=2l -> one
    // coalesced 512 B transaction per row.
    {
        const float* W1o = W1 + (size_t)o * MID_DIM * IN_DIM;
        const float2 xv = ((const float2*)s_x)[l];
        #pragma unroll 4
        for (int i = 0; i < 64; ++i) {
            const int r = w * 64 + i;
            float2 wv = ((const float2*)(W1o + (size_t)r * IN_DIM))[l];
            float p = wv.x * xv.x + wv.y * xv.y;
            #pragma unroll
            for (int off = 32; off > 0; off >>= 1)
                p += __shfl_down(p, off, 64);
            if (l == 0) s_y1[r] = p + b1[(size_t)o * MID_DIM + r];
        }
    }
    __syncthreads();

    // ----- Layer 2: y2[r] = sigmoid(dot(y1, W2[o,r,:]) + b2[o,r]) -----
    // Lane l reads float4 at k=4l -> one coalesced 1 KB transaction per row.
    {
        const float* W2o = W2 + (size_t)o * MID_DIM * MID_DIM;
        const float4 yv = ((const float4*)s_y1)[l];
        #pragma unroll 4
        for (int i = 0; i < 64; ++i) {
            const int r = w * 64 + i;
            float4 wv = ((const float4*)(W2o + (size_t)r * MID_DIM))[l];
            float p = wv.x * yv.x + wv.y * yv.y + wv.z * yv.z + wv.w * yv.w;
            #pragma unroll
            for (int off = 32; off > 0; off >>= 1)
                p += __shfl_down(p, off, 64);
            if (l == 0) {
                float a = p + b2[(size_t)o * MID_DIM + r];
                s_y2[r] = 1.0f / (1.0f + expf(-a));
            }
        }
    }
    __syncthreads();

    // ----- Layer 3: out[o] = sigmoid(dot(y2, W3[o,0,:]) + b3[o]) -----
    // Thread t reads W3[o,t]: consecutive lanes, consecutive addresses.
    {
        float p = s_y2[t] * W3[(size_t)o * MID_DIM + t];
        #pragma unroll
        for (int off = 32; off > 0; off >>= 1)
            p += __shfl_down(p, off, 64);
        if (l == 0) s_red[w] = p;
        __syncthreads();
        if (t == 0) {
            float s = s_red[0] + s_red[1] + s_red[2] + s_red[3] + b3[o];
            out[o] = 1.0f / (1.0f + expf(-s));
        }
    }
}

extern "C" void kernel_launch(void* const* d_in, const int* in_sizes, int n_in,
                              void* d_out, int out_size, void* d_ws, size_t ws_size,
                              hipStream_t stream) {
    const float* x  = (const float*)d_in[0];
    const float* W1 = (const float*)d_in[1];
    const float* b1 = (const float*)d_in[2];
    const float* W2 = (const float*)d_in[3];
    const float* b2 = (const float*)d_in[4];
    const float* W3 = (const float*)d_in[5];
    const float* b3 = (const float*)d_in[6];
    float* out = (float*)d_out;

    mlp_grouped_kernel<<<N_OBJ, 256, 0, stream>>>(x, W1, b1, W2, b2, W3, b3, out);
}